// Round 1
// baseline (110.397 us; speedup 1.0000x reference)
//
#include <hip/hip_runtime.h>
#include <math.h>

#define MAXG 1024
#define CH 256
#define EPS_T 1e-4f

// ws layout: 12 float arrays of [B*G] each (attr-major), then B ints (valid counts).
// attrs: 0 mx, 1 my, 2 conA, 3 conB, 4 conC, 5 tz, 6 op, 7 c0, 8 c1, 9 c2, 10 rx, 11 ry

__global__ __launch_bounds__(1024) void prep_kernel(
    const float* __restrict__ extr,
    const float* __restrict__ intr,
    const float* __restrict__ nearv,
    const int* __restrict__ hp,
    const int* __restrict__ wp,
    const float* __restrict__ means,
    const float* __restrict__ covs,
    const float* __restrict__ shs,
    const float* __restrict__ opac,
    float* __restrict__ ws,
    int B, int G)
{
  const int b = blockIdx.x;
  const int tid = threadIdx.x;
  const int BG = B * G;

  __shared__ float s_attr[12][MAXG];
  __shared__ float s_key[MAXG];
  __shared__ int   s_idx[MAXG];
  __shared__ int   s_cnt;

  const float hf = (float)hp[0];
  const float wf = (float)wp[0];
  const float scale = 1.0f / nearv[b];
  const float s2 = scale * scale;

  // affine inverse of scaled extrinsics: view = inv([A, t; 0, 1])
  const float* E = extr + b * 16;
  const float A00=E[0], A01=E[1], A02=E[2];
  const float A10=E[4], A11=E[5], A12=E[6];
  const float A20=E[8], A21=E[9], A22=E[10];
  const float te0=E[3]*scale, te1=E[7]*scale, te2=E[11]*scale;
  const float co00 =  (A11*A22 - A12*A21);
  const float co10 = -(A10*A22 - A12*A20);
  const float co20 =  (A10*A21 - A11*A20);
  const float detA = A00*co00 + A01*co10 + A02*co20;
  const float idA = 1.0f / detA;
  const float R00 = co00*idA;
  const float R01 = -(A01*A22 - A02*A21)*idA;
  const float R02 =  (A01*A12 - A02*A11)*idA;
  const float R10 = co10*idA;
  const float R11 =  (A00*A22 - A02*A20)*idA;
  const float R12 = -(A00*A12 - A02*A10)*idA;
  const float R20 = co20*idA;
  const float R21 = -(A00*A21 - A01*A20)*idA;
  const float R22 =  (A00*A11 - A01*A10)*idA;
  const float t0 = -(R00*te0 + R01*te1 + R02*te2);
  const float t1 = -(R10*te0 + R11*te1 + R12*te2);
  const float t2 = -(R20*te0 + R21*te1 + R22*te2);

  const float fx = intr[b*9+0], fy = intr[b*9+4];
  const float cx = intr[b*9+2], cy = intr[b*9+5];
  const float fx_p = fx*wf, fy_p = fy*hf, cx_p = cx*wf, cy_p = cy*hf;
  const float lim_x = 1.3f*0.5f/fx, lim_y = 1.3f*0.5f/fy;

  if (tid == 0) s_cnt = 0;
  __syncthreads();

  for (int g = tid; g < MAXG; g += blockDim.x) {
    float key = INFINITY;
    if (g < G) {
      const float* mp = means + ((size_t)(b*G + g))*3;
      float m0 = mp[0]*scale, m1 = mp[1]*scale, m2 = mp[2]*scale;
      float camx = R00*m0 + R01*m1 + R02*m2 + t0;
      float camy = R10*m0 + R11*m1 + R12*m2 + t1;
      float tz   = R20*m0 + R21*m1 + R22*m2 + t2;
      float itz = 1.0f / tz;
      const float* Cp = covs + ((size_t)(b*G + g))*9;
      float C00=Cp[0]*s2, C01=Cp[1]*s2, C02=Cp[2]*s2;
      float C10=Cp[3]*s2, C11=Cp[4]*s2, C12=Cp[5]*s2;
      float C20=Cp[6]*s2, C21=Cp[7]*s2, C22=Cp[8]*s2;
      float txz = fminf(fmaxf(camx*itz, -lim_x), lim_x) * tz;
      float tyz = fminf(fmaxf(camy*itz, -lim_y), lim_y) * tz;
      float j00 = fx_p*itz, j02 = -fx_p*txz*itz*itz;
      float j11 = fy_p*itz, j12 = -fy_p*tyz*itz*itz;
      // M = J * R  (2x3)
      float M00 = j00*R00 + j02*R20;
      float M01 = j00*R01 + j02*R21;
      float M02 = j00*R02 + j02*R22;
      float M10 = j11*R10 + j12*R20;
      float M11 = j11*R11 + j12*R21;
      float M12 = j11*R12 + j12*R22;
      // cov2d = M C M^T
      float v0 = C00*M00 + C01*M01 + C02*M02;
      float v1 = C10*M00 + C11*M01 + C12*M02;
      float v2 = C20*M00 + C21*M01 + C22*M02;
      float u0 = C00*M10 + C01*M11 + C02*M12;
      float u1 = C10*M10 + C11*M11 + C12*M12;
      float u2 = C20*M10 + C21*M11 + C22*M12;
      float a  = M00*v0 + M01*v1 + M02*v2 + 0.3f;
      float bb = M00*u0 + M01*u1 + M02*u2;
      float c  = M10*u0 + M11*u1 + M12*u2 + 0.3f;
      float det2 = a*c - bb*bb;
      float invd = (det2 != 0.0f) ? (1.0f/det2) : 0.0f;
      float conA = c*invd, conB = -bb*invd, conC = a*invd;
      float mx = fx_p*camx*itz + cx_p - 0.5f;
      float my = fy_p*camy*itz + cy_p - 0.5f;
      float op = opac[b*G + g];
      const float* sp = shs + ((size_t)(b*G + g))*3;
      float col0 = fmaxf(0.28209479177387814f*sp[0] + 0.5f, 0.0f);
      float col1 = fmaxf(0.28209479177387814f*sp[1] + 0.5f, 0.0f);
      float col2 = fmaxf(0.28209479177387814f*sp[2] + 0.5f, 0.0f);
      // max radius where alpha >= 1/255 can hold: q <= 2*ln(255*op)
      float r2max = 2.0f * logf(255.0f * op);
      bool valid = (tz > 0.2f) && (det2 > 0.0f) && (r2max > 0.0f);
      if (valid) {
        key = tz;
        atomicAdd(&s_cnt, 1);
      }
      float rx = sqrtf(fmaxf(r2max*a, 0.0f)) + 0.01f;
      float ry = sqrtf(fmaxf(r2max*c, 0.0f)) + 0.01f;
      s_attr[0][g]=mx;   s_attr[1][g]=my;   s_attr[2][g]=conA; s_attr[3][g]=conB;
      s_attr[4][g]=conC; s_attr[5][g]=tz;   s_attr[6][g]=op;
      s_attr[7][g]=col0; s_attr[8][g]=col1; s_attr[9][g]=col2;
      s_attr[10][g]=rx;  s_attr[11][g]=ry;
    }
    s_key[g] = key;
    s_idx[g] = g;
  }
  __syncthreads();

  // bitonic sort ascending by key over MAXG elements
  for (int k2 = 2; k2 <= MAXG; k2 <<= 1) {
    for (int j = k2 >> 1; j > 0; j >>= 1) {
      for (int i = tid; i < MAXG; i += blockDim.x) {
        int ixj = i ^ j;
        if (ixj > i) {
          float ki = s_key[i], kj = s_key[ixj];
          bool up = ((i & k2) == 0);
          if (up ? (ki > kj) : (ki < kj)) {
            s_key[i] = kj; s_key[ixj] = ki;
            int tmp = s_idx[i]; s_idx[i] = s_idx[ixj]; s_idx[ixj] = tmp;
          }
        }
      }
      __syncthreads();
    }
  }

  // write reordered SoA
  for (int i = tid; i < G; i += blockDim.x) {
    int j = s_idx[i];
    #pragma unroll
    for (int k = 0; k < 12; k++)
      ws[k*BG + b*G + i] = s_attr[k][j];
  }
  if (tid == 0) ((int*)ws)[12*BG + b] = s_cnt;
}

__global__ __launch_bounds__(256) void render_kernel(
    const float* __restrict__ ws,
    const float* __restrict__ bg,
    const int* __restrict__ hp,
    const int* __restrict__ wp,
    float* __restrict__ out,
    int B, int G, int hw)
{
  const int tid = threadIdx.x;
  const int lane = tid & 63;
  const int wv = tid >> 6;
  const int tiles_per_img = hw >> 8;
  const int b = blockIdx.x / tiles_per_img;
  const int tile = blockIdx.x % tiles_per_img;
  const int w = wp[0];
  const int tiles_x = w >> 4;
  const int tx = tile % tiles_x;
  const int ty = tile / tiles_x;
  const int qx = (wv & 1) << 3;
  const int qy = (wv >> 1) << 3;
  const int px = (tx << 4) + qx + (lane & 7);
  const int py = (ty << 4) + qy + (lane >> 3);
  const float pxf = (float)px, pyf = (float)py;
  // wave's 8x8 quadrant bbox (pixel centers), small pad for safety
  const float bx0 = (float)((tx << 4) + qx) - 0.01f;
  const float bx1 = bx0 + 7.02f;
  const float by0 = (float)((ty << 4) + qy) - 0.01f;
  const float by1 = by0 + 7.02f;

  const int BG = B * G;
  const int base = b * G;
  const int nv = ((const int*)ws)[12*BG + b];

  __shared__ float s[12][CH];
  __shared__ int s_list[4][CH];
  __shared__ int s_alive;

  float T = 1.0f, c0a = 0.f, c1a = 0.f, c2a = 0.f, da = 0.f, wa = 0.f;
  if (tid == 0) s_alive = 0;

  for (int cstart = 0; cstart < nv; cstart += CH) {
    const int clen = min(CH, nv - cstart);
    if (tid < clen) {
      #pragma unroll
      for (int k = 0; k < 12; k++)
        s[k][tid] = ws[k*BG + base + cstart + tid];
    }
    __syncthreads();

    // per-wave cull + order-preserving compaction into s_list[wv]
    int cnt = 0;
    for (int s0 = 0; s0 < clen; s0 += 64) {
      const int j = s0 + lane;
      bool surv = false;
      if (j < clen) {
        float gx = s[0][j], gy = s[1][j];
        float rx = s[10][j], ry = s[11][j];
        surv = (gx - rx <= bx1) && (gx + rx >= bx0) &&
               (gy - ry <= by1) && (gy + ry >= by0);
      }
      unsigned long long m = __ballot(surv);
      if (surv) {
        int pos = cnt + __popcll(m & ((1ull << lane) - 1ull));
        s_list[wv][pos] = j;
      }
      cnt += __popcll(m);
    }

    if (__ballot(T >= EPS_T) != 0ull) {
      for (int i = 0; i < cnt; i++) {
        const int j = s_list[wv][i];
        const float dx = pxf - s[0][j];
        const float dy = pyf - s[1][j];
        const float q = s[2][j]*dx*dx + 2.0f*s[3][j]*dx*dy + s[4][j]*dy*dy;
        if (q >= 0.0f) {  // power = -0.5q <= 0
          float al = fminf(s[6][j]*__expf(-0.5f*q), 0.99f);
          if (al >= (1.0f/255.0f) && T >= EPS_T) {
            const float wgt = al * T;
            c0a += wgt * s[7][j];
            c1a += wgt * s[8][j];
            c2a += wgt * s[9][j];
            da  += wgt * s[5][j];
            wa  += wgt;
            T *= (1.0f - al);
          }
        }
      }
    }

    if (T >= EPS_T) s_alive = 1;
    __syncthreads();
    const int alive = s_alive;
    __syncthreads();
    if (tid == 0) s_alive = 0;
    if (!alive) break;
  }

  const int pixidx = py * w + px;
  const size_t io = (size_t)b * 3 * hw;
  out[io + 0*(size_t)hw + pixidx] = c0a + T * bg[b*3+0];
  out[io + 1*(size_t)hw + pixidx] = c1a + T * bg[b*3+1];
  out[io + 2*(size_t)hw + pixidx] = c2a + T * bg[b*3+2];
  out[(size_t)B*3*hw + (size_t)b*hw + pixidx] = da;
  out[(size_t)B*4*hw + (size_t)b*hw + pixidx] = wa;
}

extern "C" void kernel_launch(void* const* d_in, const int* in_sizes, int n_in,
                              void* d_out, int out_size, void* d_ws, size_t ws_size,
                              hipStream_t stream) {
  const float* extr  = (const float*)d_in[0];
  const float* intr  = (const float*)d_in[1];
  const float* nearv = (const float*)d_in[2];
  const int*   hp    = (const int*)d_in[4];
  const int*   wp    = (const int*)d_in[5];
  const float* bg    = (const float*)d_in[6];
  const float* means = (const float*)d_in[7];
  const float* covs  = (const float*)d_in[8];
  const float* shs   = (const float*)d_in[9];
  const float* opac  = (const float*)d_in[10];

  const int B  = in_sizes[2];
  const int G  = in_sizes[10] / B;
  const int hw = out_size / (5 * B);

  float* ws  = (float*)d_ws;
  float* out = (float*)d_out;

  prep_kernel<<<B, 1024, 0, stream>>>(extr, intr, nearv, hp, wp,
                                      means, covs, shs, opac, ws, B, G);
  const int tiles = hw / 256;
  render_kernel<<<B * tiles, 256, 0, stream>>>(ws, bg, hp, wp, out, B, G, hw);
}

// Round 2
// 96.563 us; speedup vs baseline: 1.1433x; 1.1433x over previous
//
#include <hip/hip_runtime.h>
#include <math.h>

#define SMAX 1024
#define EPS_T 1e-4f

// ws layout (per gaussian index i in [0, B*G)):
//   comp:  float4[3] per gaussian at ws + i*12 floats
//          [0]=(mx,my,conA,conB) [1]=(conC,op,c0,c1) [2]=(c2,tz,-,-)
//   cull:  float4 per gaussian at ws + BG*12 floats: (mx, my, rx, ry); invalid -> mx=1e9
//   tz:    float per gaussian at ws + BG*16 floats

__global__ __launch_bounds__(256) void prep_kernel(
    const float* __restrict__ extr,
    const float* __restrict__ intr,
    const float* __restrict__ nearv,
    const int* __restrict__ hp,
    const int* __restrict__ wp,
    const float* __restrict__ means,
    const float* __restrict__ covs,
    const float* __restrict__ shs,
    const float* __restrict__ opac,
    float* __restrict__ ws,
    int B, int G)
{
  const int i = blockIdx.x * blockDim.x + threadIdx.x;
  const int BG = B * G;
  if (i >= BG) return;
  const int b = i / G;

  const float hf = (float)hp[0];
  const float wf = (float)wp[0];
  const float scale = 1.0f / nearv[b];
  const float s2 = scale * scale;

  // affine inverse of scaled extrinsics
  const float* E = extr + b * 16;
  const float A00=E[0], A01=E[1], A02=E[2];
  const float A10=E[4], A11=E[5], A12=E[6];
  const float A20=E[8], A21=E[9], A22=E[10];
  const float te0=E[3]*scale, te1=E[7]*scale, te2=E[11]*scale;
  const float co00 =  (A11*A22 - A12*A21);
  const float co10 = -(A10*A22 - A12*A20);
  const float co20 =  (A10*A21 - A11*A20);
  const float idA = 1.0f / (A00*co00 + A01*co10 + A02*co20);
  const float R00 = co00*idA;
  const float R01 = -(A01*A22 - A02*A21)*idA;
  const float R02 =  (A01*A12 - A02*A11)*idA;
  const float R10 = co10*idA;
  const float R11 =  (A00*A22 - A02*A20)*idA;
  const float R12 = -(A00*A12 - A02*A10)*idA;
  const float R20 = co20*idA;
  const float R21 = -(A00*A21 - A01*A20)*idA;
  const float R22 =  (A00*A11 - A01*A10)*idA;
  const float t0 = -(R00*te0 + R01*te1 + R02*te2);
  const float t1 = -(R10*te0 + R11*te1 + R12*te2);
  const float t2 = -(R20*te0 + R21*te1 + R22*te2);

  const float fx = intr[b*9+0], fy = intr[b*9+4];
  const float cx = intr[b*9+2], cy = intr[b*9+5];
  const float fx_p = fx*wf, fy_p = fy*hf, cx_p = cx*wf, cy_p = cy*hf;
  const float lim_x = 1.3f*0.5f/fx, lim_y = 1.3f*0.5f/fy;

  const float* mp = means + (size_t)i*3;
  float m0 = mp[0]*scale, m1 = mp[1]*scale, m2 = mp[2]*scale;
  float camx = R00*m0 + R01*m1 + R02*m2 + t0;
  float camy = R10*m0 + R11*m1 + R12*m2 + t1;
  float tz   = R20*m0 + R21*m1 + R22*m2 + t2;
  float itz = 1.0f / tz;
  const float* Cp = covs + (size_t)i*9;
  float C00=Cp[0]*s2, C01=Cp[1]*s2, C02=Cp[2]*s2;
  float C10=Cp[3]*s2, C11=Cp[4]*s2, C12=Cp[5]*s2;
  float C20=Cp[6]*s2, C21=Cp[7]*s2, C22=Cp[8]*s2;
  float txz = fminf(fmaxf(camx*itz, -lim_x), lim_x) * tz;
  float tyz = fminf(fmaxf(camy*itz, -lim_y), lim_y) * tz;
  float j00 = fx_p*itz, j02 = -fx_p*txz*itz*itz;
  float j11 = fy_p*itz, j12 = -fy_p*tyz*itz*itz;
  float M00 = j00*R00 + j02*R20;
  float M01 = j00*R01 + j02*R21;
  float M02 = j00*R02 + j02*R22;
  float M10 = j11*R10 + j12*R20;
  float M11 = j11*R11 + j12*R21;
  float M12 = j11*R12 + j12*R22;
  float v0 = C00*M00 + C01*M01 + C02*M02;
  float v1 = C10*M00 + C11*M01 + C12*M02;
  float v2 = C20*M00 + C21*M01 + C22*M02;
  float u0 = C00*M10 + C01*M11 + C02*M12;
  float u1 = C10*M10 + C11*M11 + C12*M12;
  float u2 = C20*M10 + C21*M11 + C22*M12;
  float a  = M00*v0 + M01*v1 + M02*v2 + 0.3f;
  float bb = M00*u0 + M01*u1 + M02*u2;
  float c  = M10*u0 + M11*u1 + M12*u2 + 0.3f;
  float det2 = a*c - bb*bb;
  float invd = (det2 != 0.0f) ? (1.0f/det2) : 0.0f;
  float conA = c*invd, conB = -bb*invd, conC = a*invd;
  float mx = fx_p*camx*itz + cx_p - 0.5f;
  float my = fy_p*camy*itz + cy_p - 0.5f;
  float op = opac[i];
  const float* sp = shs + (size_t)i*3;
  float col0 = fmaxf(0.28209479177387814f*sp[0] + 0.5f, 0.0f);
  float col1 = fmaxf(0.28209479177387814f*sp[1] + 0.5f, 0.0f);
  float col2 = fmaxf(0.28209479177387814f*sp[2] + 0.5f, 0.0f);
  float r2max = 2.0f * logf(255.0f * op);
  bool valid = (tz > 0.2f) && (det2 > 0.0f) && (r2max > 0.0f);
  float rx = sqrtf(fmaxf(r2max*a, 0.0f)) + 0.01f;
  float ry = sqrtf(fmaxf(r2max*c, 0.0f)) + 0.01f;

  float4* compv = (float4*)ws;
  compv[(size_t)i*3+0] = make_float4(mx, my, conA, conB);
  compv[(size_t)i*3+1] = make_float4(conC, op, col0, col1);
  compv[(size_t)i*3+2] = make_float4(col2, tz, 0.f, 0.f);
  float4* cullv = (float4*)(ws + (size_t)BG*12);
  cullv[i] = make_float4(valid ? mx : 1e9f, my, rx, ry);
  ws[(size_t)BG*16 + i] = tz;
}

__global__ __launch_bounds__(256) void render_kernel(
    const float* __restrict__ ws,
    const float* __restrict__ bg,
    const int* __restrict__ wp,
    float* __restrict__ out,
    int B, int G, int hw)
{
  const int tid = threadIdx.x;
  const int lane = tid & 63;
  const int wv = tid >> 6;
  const int tiles_per_img = hw >> 8;
  const int b = blockIdx.x / tiles_per_img;
  const int tile = blockIdx.x % tiles_per_img;
  const int w = wp[0];
  const int tiles_x = w >> 4;
  const int tx = tile % tiles_x;
  const int ty = tile / tiles_x;
  const int qx = (wv & 1) << 3;
  const int qy = (wv >> 1) << 3;
  const int px = (tx << 4) + qx + (lane & 7);
  const int py = (ty << 4) + qy + (lane >> 3);
  const float pxf = (float)px, pyf = (float)py;
  const float bx0 = (float)((tx << 4) + qx) - 0.01f;
  const float bx1 = bx0 + 7.02f;
  const float by0 = (float)((ty << 4) + qy) - 0.01f;
  const float by1 = by0 + 7.02f;

  const int BG = B * G;
  const int base = b * G;
  const float4* compv = (const float4*)ws;
  const float4* cullv = (const float4*)(ws + (size_t)BG*12);
  const float*  tza   = ws + (size_t)BG*16;

  __shared__ float  s_key[4][SMAX];
  __shared__ int    s_idx[4][SMAX];
  __shared__ float4 s_c[4][64][3];

  // ---- collect survivors for this wave's 8x8 quadrant (order-preserving) ----
  int cnt = 0;
  for (int g0 = 0; g0 < G; g0 += 64) {
    const int g = g0 + lane;
    bool surv = false;
    if (g < G) {
      float4 cu = cullv[base + g];
      surv = (cu.x - cu.z <= bx1) && (cu.x + cu.z >= bx0) &&
             (cu.y - cu.w <= by1) && (cu.y + cu.w >= by0);
    }
    unsigned long long m = __ballot(surv);
    if (surv) {
      int pos = cnt + __popcll(m & ((1ull << lane) - 1ull));
      if (pos < SMAX) {
        s_key[wv][pos] = tza[base + g];
        s_idx[wv][pos] = g;
      }
    }
    cnt += __popcll(m);
  }
  cnt = min(cnt, SMAX);

  float T = 1.0f, a0 = 0.f, a1 = 0.f, a2 = 0.f, da = 0.f, wa = 0.f;

  if (cnt > 0) {
    // pad to power of two
    int n2 = 1;
    while (n2 < cnt) n2 <<= 1;
    for (int i2 = cnt + lane; i2 < n2; i2 += 64) {
      s_key[wv][i2] = INFINITY;
      s_idx[wv][i2] = 0x7fffffff;
    }
    __builtin_amdgcn_wave_barrier();

    // per-wave bitonic sort ascending by (tz, idx) — wave-synchronous LDS
    for (int k2 = 2; k2 <= n2; k2 <<= 1) {
      for (int j = k2 >> 1; j > 0; j >>= 1) {
        for (int i2 = lane; i2 < n2; i2 += 64) {
          int ixj = i2 ^ j;
          if (ixj > i2) {
            float ki = s_key[wv][i2], kj = s_key[wv][ixj];
            int   ii = s_idx[wv][i2], ij = s_idx[wv][ixj];
            bool up = ((i2 & k2) == 0);
            bool gt = (ki > kj) || (ki == kj && ii > ij);
            if (up ? gt : !gt && !(ki == kj && ii == ij)) {
              s_key[wv][i2] = kj; s_key[wv][ixj] = ki;
              s_idx[wv][i2] = ij; s_idx[wv][ixj] = ii;
            }
          }
        }
        __builtin_amdgcn_wave_barrier();
      }
    }

    // ---- composite in sorted order, 64-entry gather chunks ----
    for (int c0 = 0; c0 < cnt; c0 += 64) {
      const int mlen = min(64, cnt - c0);
      if (lane < mlen) {
        const int g = s_idx[wv][c0 + lane];
        const float4* cp = compv + (size_t)(base + g) * 3;
        s_c[wv][lane][0] = cp[0];
        s_c[wv][lane][1] = cp[1];
        s_c[wv][lane][2] = cp[2];
      }
      __builtin_amdgcn_wave_barrier();
      for (int i2 = 0; i2 < mlen; i2++) {
        const float4 A  = s_c[wv][i2][0];
        const float4 Bv = s_c[wv][i2][1];
        const float4 Cv = s_c[wv][i2][2];
        const float dx = pxf - A.x;
        const float dy = pyf - A.y;
        const float q = A.z*dx*dx + 2.0f*A.w*dx*dy + Bv.x*dy*dy;
        if (q >= 0.0f && T >= EPS_T) {
          float al = fminf(Bv.y * __expf(-0.5f*q), 0.99f);
          if (al >= (1.0f/255.0f)) {
            const float wgt = al * T;
            a0 += wgt * Bv.z;
            a1 += wgt * Bv.w;
            a2 += wgt * Cv.x;
            da += wgt * Cv.y;
            wa += wgt;
            T *= (1.0f - al);
          }
        }
      }
      if (__ballot(T >= EPS_T) == 0ull) break;
      __builtin_amdgcn_wave_barrier();
    }
  }

  const int pixidx = py * w + px;
  const size_t io = (size_t)b * 3 * hw;
  out[io + 0*(size_t)hw + pixidx] = a0 + T * bg[b*3+0];
  out[io + 1*(size_t)hw + pixidx] = a1 + T * bg[b*3+1];
  out[io + 2*(size_t)hw + pixidx] = a2 + T * bg[b*3+2];
  out[(size_t)B*3*hw + (size_t)b*hw + pixidx] = da;
  out[(size_t)B*4*hw + (size_t)b*hw + pixidx] = wa;
}

extern "C" void kernel_launch(void* const* d_in, const int* in_sizes, int n_in,
                              void* d_out, int out_size, void* d_ws, size_t ws_size,
                              hipStream_t stream) {
  const float* extr  = (const float*)d_in[0];
  const float* intr  = (const float*)d_in[1];
  const float* nearv = (const float*)d_in[2];
  const int*   hp    = (const int*)d_in[4];
  const int*   wp    = (const int*)d_in[5];
  const float* bg    = (const float*)d_in[6];
  const float* means = (const float*)d_in[7];
  const float* covs  = (const float*)d_in[8];
  const float* shs   = (const float*)d_in[9];
  const float* opac  = (const float*)d_in[10];

  const int B  = in_sizes[2];
  const int G  = in_sizes[10] / B;
  const int hw = out_size / (5 * B);

  float* ws  = (float*)d_ws;
  float* out = (float*)d_out;

  const int BG = B * G;
  prep_kernel<<<(BG + 255) / 256, 256, 0, stream>>>(
      extr, intr, nearv, hp, wp, means, covs, shs, opac, ws, B, G);
  const int tiles = hw / 256;
  render_kernel<<<B * tiles, 256, 0, stream>>>(ws, bg, wp, out, B, G, hw);
}

// Round 3
// 94.915 us; speedup vs baseline: 1.1631x; 1.0174x over previous
//
#include <hip/hip_runtime.h>
#include <math.h>

#define G_MAX 1024
#define SMAX 256
#define EPS_T 1e-4f

// Single fused kernel: per-block prep of the whole batch into LDS (redundant
// across blocks -- 20 MFLOP total, trivial), then per-wave cull -> sort ->
// composite for one 8x8 pixel quadrant. No workspace, no second launch.

__global__ __launch_bounds__(256) void render_all(
    const float* __restrict__ extr,
    const float* __restrict__ intr,
    const float* __restrict__ nearv,
    const int* __restrict__ hp,
    const int* __restrict__ wp,
    const float* __restrict__ bg,
    const float* __restrict__ means,
    const float* __restrict__ covs,
    const float* __restrict__ shs,
    const float* __restrict__ opac,
    float* __restrict__ out,
    int B, int G, int hw)
{
  const int tid = threadIdx.x;
  const int lane = tid & 63;
  const int wv = tid >> 6;
  const int tiles_per_img = hw >> 8;
  const int b = blockIdx.x / tiles_per_img;
  const int tile = blockIdx.x % tiles_per_img;
  const int w = wp[0];
  const int tiles_x = w >> 4;
  const int tx = tile % tiles_x;
  const int ty = tile / tiles_x;
  const int qx = (wv & 1) << 3;
  const int qy = (wv >> 1) << 3;
  const int px = (tx << 4) + qx + (lane & 7);
  const int py = (ty << 4) + qy + (lane >> 3);
  const float pxf = (float)px, pyf = (float)py;
  const float bx0 = (float)((tx << 4) + qx) - 0.01f;
  const float bx1 = bx0 + 7.02f;
  const float by0 = (float)((ty << 4) + qy) - 0.01f;
  const float by1 = by0 + 7.02f;

  __shared__ float4 s_cull[G_MAX];                 // (mx|1e9, my, rx, ry)
  __shared__ float4 s_con [G_MAX];                 // (conA, conB, conC, op)
  __shared__ float4 s_col [G_MAX];                 // (c0, c1, c2, tz)
  __shared__ unsigned long long s_srt[4][SMAX];    // (tz_bits<<32)|idx per wave

  // ---- per-block camera setup (uniform -> scalar unit) ----
  const float hf = (float)hp[0];
  const float wf = (float)wp[0];
  const float scale = 1.0f / nearv[b];
  const float s2 = scale * scale;
  const float* E = extr + b * 16;
  const float A00=E[0], A01=E[1], A02=E[2];
  const float A10=E[4], A11=E[5], A12=E[6];
  const float A20=E[8], A21=E[9], A22=E[10];
  const float te0=E[3]*scale, te1=E[7]*scale, te2=E[11]*scale;
  const float co00 =  (A11*A22 - A12*A21);
  const float co10 = -(A10*A22 - A12*A20);
  const float co20 =  (A10*A21 - A11*A20);
  const float idA = 1.0f / (A00*co00 + A01*co10 + A02*co20);
  const float R00 = co00*idA;
  const float R01 = -(A01*A22 - A02*A21)*idA;
  const float R02 =  (A01*A12 - A02*A11)*idA;
  const float R10 = co10*idA;
  const float R11 =  (A00*A22 - A02*A20)*idA;
  const float R12 = -(A00*A12 - A02*A10)*idA;
  const float R20 = co20*idA;
  const float R21 = -(A00*A21 - A01*A20)*idA;
  const float R22 =  (A00*A11 - A01*A10)*idA;
  const float t0 = -(R00*te0 + R01*te1 + R02*te2);
  const float t1 = -(R10*te0 + R11*te1 + R12*te2);
  const float t2 = -(R20*te0 + R21*te1 + R22*te2);
  const float fx = intr[b*9+0], fy = intr[b*9+4];
  const float cx = intr[b*9+2], cy = intr[b*9+5];
  const float fx_p = fx*wf, fy_p = fy*hf, cx_p = cx*wf, cy_p = cy*hf;
  const float lim_x = 1.3f*0.5f/fx, lim_y = 1.3f*0.5f/fy;

  // ---- prep phase: whole batch into LDS ----
  for (int g = tid; g < G; g += blockDim.x) {
    const int i = b * G + g;
    const float* mp = means + (size_t)i*3;
    float m0 = mp[0]*scale, m1 = mp[1]*scale, m2 = mp[2]*scale;
    float camx = R00*m0 + R01*m1 + R02*m2 + t0;
    float camy = R10*m0 + R11*m1 + R12*m2 + t1;
    float tz   = R20*m0 + R21*m1 + R22*m2 + t2;
    float itz = 1.0f / tz;
    const float* Cp = covs + (size_t)i*9;
    float C00=Cp[0]*s2, C01=Cp[1]*s2, C02=Cp[2]*s2;
    float C10=Cp[3]*s2, C11=Cp[4]*s2, C12=Cp[5]*s2;
    float C20=Cp[6]*s2, C21=Cp[7]*s2, C22=Cp[8]*s2;
    float txz = fminf(fmaxf(camx*itz, -lim_x), lim_x) * tz;
    float tyz = fminf(fmaxf(camy*itz, -lim_y), lim_y) * tz;
    float j00 = fx_p*itz, j02 = -fx_p*txz*itz*itz;
    float j11 = fy_p*itz, j12 = -fy_p*tyz*itz*itz;
    float M00 = j00*R00 + j02*R20;
    float M01 = j00*R01 + j02*R21;
    float M02 = j00*R02 + j02*R22;
    float M10 = j11*R10 + j12*R20;
    float M11 = j11*R11 + j12*R21;
    float M12 = j11*R12 + j12*R22;
    float v0 = C00*M00 + C01*M01 + C02*M02;
    float v1 = C10*M00 + C11*M01 + C12*M02;
    float v2 = C20*M00 + C21*M01 + C22*M02;
    float u0 = C00*M10 + C01*M11 + C02*M12;
    float u1 = C10*M10 + C11*M11 + C12*M12;
    float u2 = C20*M10 + C21*M11 + C22*M12;
    float a  = M00*v0 + M01*v1 + M02*v2 + 0.3f;
    float bb = M00*u0 + M01*u1 + M02*u2;
    float c  = M10*u0 + M11*u1 + M12*u2 + 0.3f;
    float det2 = a*c - bb*bb;
    float invd = (det2 != 0.0f) ? (1.0f/det2) : 0.0f;
    float conA = c*invd, conB = -bb*invd, conC = a*invd;
    float mx = fx_p*camx*itz + cx_p - 0.5f;
    float my = fy_p*camy*itz + cy_p - 0.5f;
    float op = opac[i];
    const float* sp = shs + (size_t)i*3;
    float col0 = fmaxf(0.28209479177387814f*sp[0] + 0.5f, 0.0f);
    float col1 = fmaxf(0.28209479177387814f*sp[1] + 0.5f, 0.0f);
    float col2 = fmaxf(0.28209479177387814f*sp[2] + 0.5f, 0.0f);
    float r2max = 2.0f * logf(255.0f * op);
    bool valid = (tz > 0.2f) && (det2 > 0.0f) && (r2max > 0.0f);
    float rx = sqrtf(fmaxf(r2max*a, 0.0f)) + 0.01f;
    float ry = sqrtf(fmaxf(r2max*c, 0.0f)) + 0.01f;
    s_cull[g] = make_float4(valid ? mx : 1e9f, my, rx, ry);
    s_con [g] = make_float4(conA, conB, conC, op);
    s_col [g] = make_float4(col0, col1, col2, tz);
  }
  __syncthreads();

  // ---- per-wave cull + order-preserving compaction (key packs tz, idx) ----
  int cnt = 0;
  for (int g0 = 0; g0 < G; g0 += 64) {
    const int g = g0 + lane;
    bool surv = false;
    float tz = 0.f;
    if (g < G) {
      float4 cu = s_cull[g];
      surv = (cu.x - cu.z <= bx1) && (cu.x + cu.z >= bx0) &&
             (cu.y - cu.w <= by1) && (cu.y + cu.w >= by0);
      tz = s_col[g].w;
    }
    unsigned long long m = __ballot(surv);
    if (surv) {
      int pos = cnt + __popcll(m & ((1ull << lane) - 1ull));
      if (pos < SMAX)
        s_srt[wv][pos] = ((unsigned long long)__float_as_uint(tz) << 32) |
                         (unsigned)g;
    }
    cnt += __popcll(m);
  }
  cnt = min(cnt, SMAX);

  float T = 1.0f, a0 = 0.f, a1 = 0.f, a2 = 0.f, da = 0.f, wa = 0.f;

  if (cnt > 0) {
    int n2 = 1;
    while (n2 < cnt) n2 <<= 1;
    for (int i2 = cnt + lane; i2 < n2; i2 += 64)
      s_srt[wv][i2] = ~0ull;
    __builtin_amdgcn_wave_barrier();

    // per-wave bitonic sort ascending on packed (tz, idx) -- wave-synchronous
    for (int k2 = 2; k2 <= n2; k2 <<= 1) {
      for (int j = k2 >> 1; j > 0; j >>= 1) {
        for (int i2 = lane; i2 < n2; i2 += 64) {
          int ixj = i2 ^ j;
          if (ixj > i2) {
            unsigned long long ka = s_srt[wv][i2];
            unsigned long long kb = s_srt[wv][ixj];
            bool up = ((i2 & k2) == 0);
            if (up ? (ka > kb) : (ka < kb)) {
              s_srt[wv][i2] = kb;
              s_srt[wv][ixj] = ka;
            }
          }
        }
        __builtin_amdgcn_wave_barrier();
      }
    }

    // ---- composite front-to-back; LDS broadcast reads ----
    for (int i2 = 0; i2 < cnt; i2++) {
      const int g = (int)(unsigned)(s_srt[wv][i2] & 0xffffffffu);
      const float4 cu = s_cull[g];
      const float4 cn = s_con[g];
      const float4 cl = s_col[g];
      const float dx = pxf - cu.x;
      const float dy = pyf - cu.y;
      const float q = cn.x*dx*dx + 2.0f*cn.y*dx*dy + cn.z*dy*dy;
      if (q >= 0.0f && T >= EPS_T) {
        float al = fminf(cn.w * __expf(-0.5f*q), 0.99f);
        if (al >= (1.0f/255.0f)) {
          const float wgt = al * T;
          a0 += wgt * cl.x;
          a1 += wgt * cl.y;
          a2 += wgt * cl.z;
          da += wgt * cl.w;
          wa += wgt;
          T *= (1.0f - al);
        }
      }
      if ((i2 & 31) == 31 && __ballot(T >= EPS_T) == 0ull) break;
    }
  }

  const int pixidx = py * w + px;
  const size_t io = (size_t)b * 3 * hw;
  out[io + 0*(size_t)hw + pixidx] = a0 + T * bg[b*3+0];
  out[io + 1*(size_t)hw + pixidx] = a1 + T * bg[b*3+1];
  out[io + 2*(size_t)hw + pixidx] = a2 + T * bg[b*3+2];
  out[(size_t)B*3*hw + (size_t)b*hw + pixidx] = da;
  out[(size_t)B*4*hw + (size_t)b*hw + pixidx] = wa;
}

extern "C" void kernel_launch(void* const* d_in, const int* in_sizes, int n_in,
                              void* d_out, int out_size, void* d_ws, size_t ws_size,
                              hipStream_t stream) {
  const float* extr  = (const float*)d_in[0];
  const float* intr  = (const float*)d_in[1];
  const float* nearv = (const float*)d_in[2];
  const int*   hp    = (const int*)d_in[4];
  const int*   wp    = (const int*)d_in[5];
  const float* bg    = (const float*)d_in[6];
  const float* means = (const float*)d_in[7];
  const float* covs  = (const float*)d_in[8];
  const float* shs   = (const float*)d_in[9];
  const float* opac  = (const float*)d_in[10];

  const int B  = in_sizes[2];
  const int G  = in_sizes[10] / B;
  const int hw = out_size / (5 * B);

  float* out = (float*)d_out;
  const int tiles = hw / 256;
  render_all<<<B * tiles, 256, 0, stream>>>(
      extr, intr, nearv, hp, wp, bg, means, covs, shs, opac, out, B, G, hw);
}